// Round 4
// baseline (401.743 us; speedup 1.0000x reference)
//
#include <hip/hip_runtime.h>
#include <stdint.h>

#define V 200000
#define E 600000
#define NB1 782          // ceil(V/256)

using bf16x8_t = __attribute__((ext_vector_type(8))) short;
using f32x4_t  = __attribute__((ext_vector_type(4))) float;

__device__ __forceinline__ unsigned short f2bf(float f) {
  unsigned int u = __float_as_uint(f);
  return (unsigned short)((u + 0x7fffu + ((u >> 16) & 1u)) >> 16);   // RNE
}

// ---------------------------------------------------------------------------
// prep_w2: fragment-linear weights so B MFMA operands are coalesced 1KB loads.
//   o = ((kg*24 + cg)*64 + lane)*8 + e
//   W[c][k], c = cg*16 + (lane&15), k = kg*32 + (lane>>4)*8 + e
//   c in [0,256) -> w0 rows; [256,384) -> w1 rows.
// ---------------------------------------------------------------------------
__global__ void prep_w2(const float* __restrict__ w0, const float* __restrict__ w1,
                        unsigned short* __restrict__ Wb2) {
  int o = blockIdx.x * 256 + threadIdx.x;        // 0..98303
  int kg = o / 12288;
  int r  = o - kg * 12288;
  int cg = r >> 9;
  int r2 = r & 511;
  int lane = r2 >> 3, e = r2 & 7;
  int c = cg * 16 + (lane & 15);
  int k = kg * 32 + (lane >> 4) * 8 + e;
  float v = (c < 256) ? w0[c * 256 + k] : w1[(c - 256) * 256 + k];
  Wb2[o] = f2bf(v);
}

// ---------------------------------------------------------------------------
// Pass 1: w1b[V,128] = bf16(verts @ w1^T + b1).  BM=64, 256 thr (4 waves x
// 32 cols). A: reg-staged fp32->bf16 into 16KB dbuf swizzled LDS. B: direct
// fragment-linear loads (L2). 6 blocks/CU.
// ---------------------------------------------------------------------------
__global__ __launch_bounds__(256, 6) void gemm_w1(
    const float* __restrict__ verts, const unsigned short* __restrict__ Wb2,
    const float* __restrict__ w1_b, unsigned short* __restrict__ w1b)
{
  __shared__ __align__(16) unsigned short As[2][64 * 64];   // 16 KB

  const int tid  = threadIdx.x;
  const int lane = tid & 63;
  const int wv   = tid >> 6;            // 0..3 -> cols [wv*32, wv*32+32)
  const int mBase = blockIdx.x * 64;

  const int srow  = tid >> 3;           // 0..31 (also +32)
  const int skseg = tid & 7;
  const float* vsrc  = verts + (size_t)(mBase + srow) * 256 + skseg * 8;
  const float* vsrc2 = vsrc + 32 * 256;
  const int sW0 = srow * 64 + ((skseg ^ (srow & 7)) * 8);   // (srow+32)&7==srow&7
  const int sW1 = sW0 + 32 * 64;

  f32x4_t acc[4][2];
  #pragma unroll
  for (int m = 0; m < 4; ++m)
    #pragma unroll
    for (int n = 0; n < 2; ++n)
      acc[m][n] = (f32x4_t){0.f, 0.f, 0.f, 0.f};

  auto Aload = [&](int kb, float4* a) {
    a[0] = *(const float4*)(vsrc  + kb * 64);
    a[1] = *(const float4*)(vsrc  + kb * 64 + 4);
    a[2] = *(const float4*)(vsrc2 + kb * 64);
    a[3] = *(const float4*)(vsrc2 + kb * 64 + 4);
  };
  auto Awrite = [&](int b, const float4* a) {
    union { unsigned short us[8]; uint4 q; } p;
    p.us[0]=f2bf(a[0].x); p.us[1]=f2bf(a[0].y); p.us[2]=f2bf(a[0].z); p.us[3]=f2bf(a[0].w);
    p.us[4]=f2bf(a[1].x); p.us[5]=f2bf(a[1].y); p.us[6]=f2bf(a[1].z); p.us[7]=f2bf(a[1].w);
    *(uint4*)&As[b][sW0] = p.q;
    p.us[0]=f2bf(a[2].x); p.us[1]=f2bf(a[2].y); p.us[2]=f2bf(a[2].z); p.us[3]=f2bf(a[2].w);
    p.us[4]=f2bf(a[3].x); p.us[5]=f2bf(a[3].y); p.us[6]=f2bf(a[3].z); p.us[7]=f2bf(a[3].w);
    *(uint4*)&As[b][sW1] = p.q;
  };
  auto compute = [&](int b, int kb) {
    #pragma unroll
    for (int kc = 0; kc < 2; ++kc) {
      bf16x8_t af[4], bfr[2];
      #pragma unroll
      for (int m = 0; m < 4; ++m) {
        int row = m * 16 + (lane & 15);
        int seg = (kc * 4 + (lane >> 4)) ^ (row & 7);
        af[m] = *(const bf16x8_t*)&As[b][row * 64 + seg * 8];
      }
      int kg = kb * 2 + kc;
      #pragma unroll
      for (int n = 0; n < 2; ++n) {
        int f = kg * 24 + 16 + wv * 2 + n;        // w1 region of Wb2
        bfr[n] = *(const bf16x8_t*)(Wb2 + (size_t)f * 512 + lane * 8);
      }
      #pragma unroll
      for (int m = 0; m < 4; ++m)
        #pragma unroll
        for (int n = 0; n < 2; ++n)
          acc[m][n] = __builtin_amdgcn_mfma_f32_16x16x32_bf16(
              af[m], bfr[n], acc[m][n], 0, 0, 0);
    }
  };

  { float4 a0[4]; Aload(0, a0); Awrite(0, a0); }
  __syncthreads();

  int buf = 0;
  #pragma unroll
  for (int kb = 0; kb < 3; ++kb) {
    float4 an[4];
    Aload(kb + 1, an);
    compute(buf, kb);
    Awrite(buf ^ 1, an);
    __syncthreads();
    buf ^= 1;
  }
  compute(buf, 3);

  const int l15 = lane & 15, lq = lane >> 4;
  #pragma unroll
  for (int n = 0; n < 2; ++n) {
    int col = wv * 32 + n * 16 + l15;             // 0..127
    float bias = w1_b[col];
    #pragma unroll
    for (int m = 0; m < 4; ++m) {
      int rb = mBase + m * 16 + lq * 4;
      #pragma unroll
      for (int r = 0; r < 4; ++r)
        w1b[(size_t)(rb + r) * 128 + col] = f2bf(acc[m][n][r] + bias);
    }
  }
}

// ---------------------------------------------------------------------------
// Pass 2: out[V,256] = verts @ w0^T + b0 + pad(segment_sum(w1b[adj])).
// BM=64, 512 thr (8 waves x 32 cols). Phase 1: per-wave gather of 8 rows'
// neighbor sums into nb[64][130] LDS (w1b is L3-resident). Phase 2: GEMM
// K-loop. Epilogue adds nb for cols<128 and writes out ONCE (no RMW pass).
// ---------------------------------------------------------------------------
__global__ __launch_bounds__(512, 6) void gemm_w0_gather(
    const float* __restrict__ verts, const unsigned short* __restrict__ Wb2,
    const float* __restrict__ w0_b, const int* __restrict__ rowptr,
    const int* __restrict__ adj, const unsigned short* __restrict__ w1b,
    float* __restrict__ out)
{
  __shared__ __align__(16) unsigned short As[2][64 * 64];   // 16 KB
  __shared__ float nb[64 * 130];                            // 33.3 KB

  const int tid  = threadIdx.x;
  const int lane = tid & 63;
  const int wv   = tid >> 6;            // 0..7 -> cols [wv*32, wv*32+32)
  const int mBase = blockIdx.x * 64;

  const int srow  = tid >> 3;           // 0..63
  const int skseg = tid & 7;
  const float* vsrc = verts + (size_t)(mBase + srow) * 256 + skseg * 8;
  const int sW0 = srow * 64 + ((skseg ^ (srow & 7)) * 8);

  f32x4_t acc[4][2];
  #pragma unroll
  for (int m = 0; m < 4; ++m)
    #pragma unroll
    for (int n = 0; n < 2; ++n)
      acc[m][n] = (f32x4_t){0.f, 0.f, 0.f, 0.f};

  auto Aload = [&](int kb, float4* a) {
    a[0] = *(const float4*)(vsrc + kb * 64);
    a[1] = *(const float4*)(vsrc + kb * 64 + 4);
  };
  auto Awrite = [&](int b, const float4* a) {
    union { unsigned short us[8]; uint4 q; } p;
    p.us[0]=f2bf(a[0].x); p.us[1]=f2bf(a[0].y); p.us[2]=f2bf(a[0].z); p.us[3]=f2bf(a[0].w);
    p.us[4]=f2bf(a[1].x); p.us[5]=f2bf(a[1].y); p.us[6]=f2bf(a[1].z); p.us[7]=f2bf(a[1].w);
    *(uint4*)&As[b][sW0] = p.q;
  };
  auto compute = [&](int b, int kb) {
    #pragma unroll
    for (int kc = 0; kc < 2; ++kc) {
      bf16x8_t af[4], bfr[2];
      #pragma unroll
      for (int m = 0; m < 4; ++m) {
        int row = m * 16 + (lane & 15);
        int seg = (kc * 4 + (lane >> 4)) ^ (row & 7);
        af[m] = *(const bf16x8_t*)&As[b][row * 64 + seg * 8];
      }
      int kg = kb * 2 + kc;
      #pragma unroll
      for (int n = 0; n < 2; ++n) {
        int f = kg * 24 + wv * 2 + n;             // w0 region of Wb2
        bfr[n] = *(const bf16x8_t*)(Wb2 + (size_t)f * 512 + lane * 8);
      }
      #pragma unroll
      for (int m = 0; m < 4; ++m)
        #pragma unroll
        for (int n = 0; n < 2; ++n)
          acc[m][n] = __builtin_amdgcn_mfma_f32_16x16x32_bf16(
              af[m], bfr[n], acc[m][n], 0, 0, 0);
    }
  };

  // Prologue A loads issued EARLY so HBM latency hides under the gather.
  float4 a0[2];
  Aload(0, a0);

  // ---- Phase 1: gather neighbor sums into nb (wave wv owns rows wv*8..+8) --
  {
    const unsigned int* w1d = (const unsigned int*)w1b;   // 64 dwords per row
    #pragma unroll 1
    for (int rr = 0; rr < 8; ++rr) {
      int lrow = wv * 8 + rr;
      int r = mBase + lrow;
      int s = rowptr[r], e = rowptr[r + 1];
      float g0 = 0.f, g1 = 0.f;
      int j = s;
      for (; j + 4 <= e; j += 4) {
        int u0 = adj[j], u1 = adj[j + 1], u2 = adj[j + 2], u3 = adj[j + 3];
        unsigned d0 = w1d[(size_t)u0 * 64 + lane];
        unsigned d1 = w1d[(size_t)u1 * 64 + lane];
        unsigned d2 = w1d[(size_t)u2 * 64 + lane];
        unsigned d3 = w1d[(size_t)u3 * 64 + lane];
        g0 += __uint_as_float(d0 << 16) + __uint_as_float(d1 << 16)
            + __uint_as_float(d2 << 16) + __uint_as_float(d3 << 16);
        g1 += __uint_as_float(d0 & 0xffff0000u) + __uint_as_float(d1 & 0xffff0000u)
            + __uint_as_float(d2 & 0xffff0000u) + __uint_as_float(d3 & 0xffff0000u);
      }
      for (; j < e; ++j) {
        unsigned d = w1d[(size_t)adj[j] * 64 + lane];
        g0 += __uint_as_float(d << 16);
        g1 += __uint_as_float(d & 0xffff0000u);
      }
      float2 g; g.x = g0; g.y = g1;
      *(float2*)&nb[lrow * 130 + lane * 2] = g;   // cols {2*lane, 2*lane+1}
    }
  }

  Awrite(0, a0);
  __syncthreads();          // covers As[0] and (transitively) nb for epilogue

  int buf = 0;
  #pragma unroll
  for (int kb = 0; kb < 3; ++kb) {
    float4 an[2];
    Aload(kb + 1, an);
    compute(buf, kb);
    Awrite(buf ^ 1, an);
    __syncthreads();
    buf ^= 1;
  }
  compute(buf, 3);

  // ---- Epilogue: out = acc + bias (+ nb for cols<128), single write ----
  const int l15 = lane & 15, lq = lane >> 4;
  #pragma unroll
  for (int n = 0; n < 2; ++n) {
    int col = wv * 32 + n * 16 + l15;             // 0..255
    float bias = w0_b[col];
    #pragma unroll
    for (int m = 0; m < 4; ++m) {
      int rb = m * 16 + lq * 4;                   // local row
      #pragma unroll
      for (int r = 0; r < 4; ++r) {
        float v = acc[m][n][r] + bias;
        if (wv < 4) v += nb[(rb + r) * 130 + col];   // wave-uniform branch
        out[(size_t)(mBase + rb + r) * 256 + col] = v;
      }
    }
  }
}

// ---------------------------------------------------------------------------
// CSR build
// ---------------------------------------------------------------------------
__global__ void count_deg(const int* __restrict__ edges, int* __restrict__ deg) {
  int i = blockIdx.x * blockDim.x + threadIdx.x;
  if (i >= 2 * E) return;
  int e = i >> 1, half = i & 1;
  atomicAdd(&deg[edges[2 * e + half]], 1);
}

__global__ void scan1(const int* __restrict__ deg, int* __restrict__ rowptr,
                      int* __restrict__ bsums) {
  __shared__ int sm[256];
  int i = blockIdx.x * 256 + threadIdx.x;
  int v = (i < V) ? deg[i] : 0;
  sm[threadIdx.x] = v;
  __syncthreads();
  for (int off = 1; off < 256; off <<= 1) {
    int t = (threadIdx.x >= off) ? sm[threadIdx.x - off] : 0;
    __syncthreads();
    sm[threadIdx.x] += t;
    __syncthreads();
  }
  if (i < V) rowptr[i] = sm[threadIdx.x] - v;
  if (threadIdx.x == 255) bsums[blockIdx.x] = sm[255];
}

__global__ void scan2(int* __restrict__ bsums) {
  __shared__ int sm[1024];
  int t = threadIdx.x;
  int v = (t < NB1) ? bsums[t] : 0;
  sm[t] = v;
  __syncthreads();
  for (int off = 1; off < 1024; off <<= 1) {
    int x = (t >= off) ? sm[t - off] : 0;
    __syncthreads();
    sm[t] += x;
    __syncthreads();
  }
  if (t < NB1) bsums[t] = sm[t] - v;
}

__global__ void scan3(int* __restrict__ rowptr, const int* __restrict__ bsums,
                      int* __restrict__ cursor) {
  int i = blockIdx.x * 256 + threadIdx.x;
  if (i < V) {
    int r = rowptr[i] + bsums[blockIdx.x];
    rowptr[i] = r;
    cursor[i] = r;
  }
  if (i == 0) rowptr[V] = 2 * E;
}

__global__ void fill_adj(const int* __restrict__ edges, int* __restrict__ cursor,
                         int* __restrict__ adj) {
  int i = blockIdx.x * blockDim.x + threadIdx.x;
  if (i >= 2 * E) return;
  int e = i >> 1, half = i & 1;
  int dst = edges[2 * e + half];
  int src = edges[2 * e + (half ^ 1)];
  adj[atomicAdd(&cursor[dst], 1)] = src;
}

// ---------------------------------------------------------------------------
extern "C" void kernel_launch(void* const* d_in, const int* in_sizes, int n_in,
                              void* d_out, int out_size, void* d_ws, size_t ws_size,
                              hipStream_t stream)
{
  const float* verts = (const float*)d_in[0];
  const int*   edges = (const int*)d_in[1];
  const float* w0_w  = (const float*)d_in[2];
  const float* w0_b  = (const float*)d_in[3];
  const float* w1_w  = (const float*)d_in[4];
  const float* w1_b  = (const float*)d_in[5];
  float* out = (float*)d_out;
  char*  ws  = (char*)d_ws;

  // workspace layout (bytes), total ~58.8 MB
  unsigned short* w1b = (unsigned short*)(ws);            // V*128*2 = 51,200,000
  int* rowptr = (int*)(ws + 51200000);                    // (V+1)*4
  int* cursor = (int*)(ws + 52000256);                    // V*4
  int* adj    = (int*)(ws + 52800256);                    // 2E*4 = 4,800,000
  int* deg    = (int*)(ws + 57600256);                    // V*4
  int* bsums  = (int*)(ws + 58400256);                    // 1024*4
  unsigned short* Wb2 = (unsigned short*)(ws + 58404352); // 98304*2*2 = 393,216

  hipMemsetAsync(deg, 0, V * sizeof(int), stream);
  prep_w2<<<384, 256, 0, stream>>>(w0_w, w1_w, Wb2);
  count_deg<<<(2 * E + 255) / 256, 256, 0, stream>>>(edges, deg);
  scan1<<<NB1, 256, 0, stream>>>(deg, rowptr, bsums);
  scan2<<<1, 1024, 0, stream>>>(bsums);
  scan3<<<NB1, 256, 0, stream>>>(rowptr, bsums, cursor);
  fill_adj<<<(2 * E + 255) / 256, 256, 0, stream>>>(edges, cursor, adj);

  gemm_w1<<<(V + 63) / 64, 256, 0, stream>>>(verts, Wb2, w1_b, w1b);

  gemm_w0_gather<<<(V + 63) / 64, 512, 0, stream>>>(
      verts, Wb2, w0_b, rowptr, adj, w1b, out);
}

// Round 5
// 384.258 us; speedup vs baseline: 1.0455x; 1.0455x over previous
//
#include <hip/hip_runtime.h>
#include <stdint.h>

#define V 200000
#define E 600000
#define NB1 782          // ceil(V/256)

using bf16x8_t = __attribute__((ext_vector_type(8))) short;
using f32x4_t  = __attribute__((ext_vector_type(4))) float;

__device__ __forceinline__ unsigned short f2bf(float f) {
  unsigned int u = __float_as_uint(f);
  return (unsigned short)((u + 0x7fffu + ((u >> 16) & 1u)) >> 16);   // RNE
}
__device__ __forceinline__ float bf2f(unsigned short s) {
  return __uint_as_float(((unsigned int)s) << 16);
}

// ---------------------------------------------------------------------------
// prep_w2: fragment-linear weights so B MFMA operands are coalesced 1KB loads.
//   o = ((kg*24 + cg)*64 + lane)*8 + e
//   W[c][k], c = cg*16 + (lane&15), k = kg*32 + (lane>>4)*8 + e
//   c in [0,256) -> w0 rows; [256,384) -> w1 rows.
// ---------------------------------------------------------------------------
__global__ void prep_w2(const float* __restrict__ w0, const float* __restrict__ w1,
                        unsigned short* __restrict__ Wb2) {
  int o = blockIdx.x * 256 + threadIdx.x;        // 0..98303
  int kg = o / 12288;
  int r  = o - kg * 12288;
  int cg = r >> 9;
  int r2 = r & 511;
  int lane = r2 >> 3, e = r2 & 7;
  int c = cg * 16 + (lane & 15);
  int k = kg * 32 + (lane >> 4) * 8 + e;
  float v = (c < 256) ? w0[c * 256 + k] : w1[(c - 256) * 256 + k];
  Wb2[o] = f2bf(v);
}

// ---------------------------------------------------------------------------
// Pass 1: w1b[V,128] = bf16(verts @ w1^T + b1).
// 512 thr (8 waves x 16 cols). Whole 64x256 A tile bursted into regs (8 x
// dwordx4 in flight per thread), staged once into 32KB swizzled LDS, ONE
// barrier, then a pure-LDS MFMA loop (B preloaded from L2).
// ---------------------------------------------------------------------------
__global__ __launch_bounds__(512, 4) void gemm_w1(
    const float* __restrict__ verts, const unsigned short* __restrict__ Wb2,
    const float* __restrict__ w1_b, unsigned short* __restrict__ w1b)
{
  __shared__ __align__(16) unsigned short As[4][64 * 64];   // 32 KB

  const int tid  = threadIdx.x;
  const int lane = tid & 63;
  const int wv   = tid >> 6;            // 0..7 -> cols [wv*16, +16)
  const int mBase = blockIdx.x * 64;
  const int srow = tid >> 3, skseg = tid & 7;
  const float* vsrc = verts + (size_t)(mBase + srow) * 256 + skseg * 8;
  const int sW = srow * 64 + ((skseg ^ (srow & 7)) * 8);

  // B preload: 8 frags (w1 region of Wb2), L2-resident
  bf16x8_t bfr[8];
  #pragma unroll
  for (int kg = 0; kg < 8; ++kg)
    bfr[kg] = *(const bf16x8_t*)(Wb2 + (size_t)(kg * 24 + 16 + wv) * 512 + lane * 8);

  // A burst: whole tile, 8 loads in flight
  float4 a[8];
  #pragma unroll
  for (int kb = 0; kb < 4; ++kb) {
    a[2 * kb]     = *(const float4*)(vsrc + kb * 64);
    a[2 * kb + 1] = *(const float4*)(vsrc + kb * 64 + 4);
  }
  #pragma unroll
  for (int kb = 0; kb < 4; ++kb) {
    union { unsigned short us[8]; uint4 q; } p;
    p.us[0]=f2bf(a[2*kb].x);   p.us[1]=f2bf(a[2*kb].y);
    p.us[2]=f2bf(a[2*kb].z);   p.us[3]=f2bf(a[2*kb].w);
    p.us[4]=f2bf(a[2*kb+1].x); p.us[5]=f2bf(a[2*kb+1].y);
    p.us[6]=f2bf(a[2*kb+1].z); p.us[7]=f2bf(a[2*kb+1].w);
    *(uint4*)&As[kb][sW] = p.q;
  }
  __syncthreads();                      // the ONLY barrier

  f32x4_t acc[4];
  #pragma unroll
  for (int m = 0; m < 4; ++m) acc[m] = (f32x4_t){0.f, 0.f, 0.f, 0.f};

  #pragma unroll
  for (int kg = 0; kg < 8; ++kg) {
    int kb = kg >> 1, kc = kg & 1;
    #pragma unroll
    for (int m = 0; m < 4; ++m) {
      int row = m * 16 + (lane & 15);
      int seg = (kc * 4 + (lane >> 4)) ^ (row & 7);
      bf16x8_t af = *(const bf16x8_t*)&As[kb][row * 64 + seg * 8];
      acc[m] = __builtin_amdgcn_mfma_f32_16x16x32_bf16(af, bfr[kg], acc[m], 0, 0, 0);
    }
  }

  const int l15 = lane & 15, lq = lane >> 4;
  int col = wv * 16 + l15;
  float bias = w1_b[col];
  #pragma unroll
  for (int m = 0; m < 4; ++m) {
    int rb = mBase + m * 16 + lq * 4;
    #pragma unroll
    for (int r = 0; r < 4; ++r)
      w1b[(size_t)(rb + r) * 128 + col] = f2bf(acc[m][r] + bias);
  }
}

// ---------------------------------------------------------------------------
// Pass 2: out[V,256] = verts @ w0^T + b0 + pad(segment_sum(w1b[adj])).
// 512 thr (8 waves x 32 cols). Order: rowptr->LDS, A burst issued (stays in
// flight), gather w1b rows (L3) into bf16 nb LDS, stage A, ONE main barrier,
// unrolled MFMA loop, fused epilogue (single out write, no RMW).
// LDS 49.7 KB -> 3 blocks/CU.
// ---------------------------------------------------------------------------
__global__ __launch_bounds__(512, 4) void gemm_w0_gather(
    const float* __restrict__ verts, const unsigned short* __restrict__ Wb2,
    const float* __restrict__ w0_b, const int* __restrict__ rowptr,
    const int* __restrict__ adj, const unsigned short* __restrict__ w1b,
    float* __restrict__ out)
{
  __shared__ __align__(16) unsigned short As[4][64 * 64];   // 32 KB
  __shared__ unsigned int nbu[64 * 65];                     // 16.6 KB (bf16 x2)
  __shared__ int rp[65];

  const int tid  = threadIdx.x;
  const int lane = tid & 63;
  const int wv   = tid >> 6;            // 0..7 -> cols [wv*32, +32)
  const int mBase = blockIdx.x * 64;
  const int srow = tid >> 3, skseg = tid & 7;
  const float* vsrc = verts + (size_t)(mBase + srow) * 256 + skseg * 8;
  const int sW = srow * 64 + ((skseg ^ (srow & 7)) * 8);

  if (tid < 65) rp[tid] = rowptr[mBase + tid];
  __syncthreads();

  // A burst: whole tile in flight during the gather
  float4 a[8];
  #pragma unroll
  for (int kb = 0; kb < 4; ++kb) {
    a[2 * kb]     = *(const float4*)(vsrc + kb * 64);
    a[2 * kb + 1] = *(const float4*)(vsrc + kb * 64 + 4);
  }

  // Gather: wave wv owns rows wv*8..+8; lane covers cols {2*lane, 2*lane+1}
  {
    const unsigned int* w1d = (const unsigned int*)w1b;   // 64 dwords per row
    #pragma unroll 1
    for (int rr = 0; rr < 8; ++rr) {
      int lrow = wv * 8 + rr;
      int s = rp[lrow], e = rp[lrow + 1];
      float g0 = 0.f, g1 = 0.f;
      int j = s;
      for (; j + 4 <= e; j += 4) {
        int u0 = adj[j], u1 = adj[j + 1], u2 = adj[j + 2], u3 = adj[j + 3];
        unsigned d0 = w1d[(size_t)u0 * 64 + lane];
        unsigned d1 = w1d[(size_t)u1 * 64 + lane];
        unsigned d2 = w1d[(size_t)u2 * 64 + lane];
        unsigned d3 = w1d[(size_t)u3 * 64 + lane];
        g0 += __uint_as_float(d0 << 16) + __uint_as_float(d1 << 16)
            + __uint_as_float(d2 << 16) + __uint_as_float(d3 << 16);
        g1 += __uint_as_float(d0 & 0xffff0000u) + __uint_as_float(d1 & 0xffff0000u)
            + __uint_as_float(d2 & 0xffff0000u) + __uint_as_float(d3 & 0xffff0000u);
      }
      for (; j < e; ++j) {
        unsigned d = w1d[(size_t)adj[j] * 64 + lane];
        g0 += __uint_as_float(d << 16);
        g1 += __uint_as_float(d & 0xffff0000u);
      }
      nbu[lrow * 65 + lane] = (unsigned)f2bf(g0) | ((unsigned)f2bf(g1) << 16);
    }
  }

  // Stage A (regs long since landed) into swizzled LDS slabs
  #pragma unroll
  for (int kb = 0; kb < 4; ++kb) {
    union { unsigned short us[8]; uint4 q; } p;
    p.us[0]=f2bf(a[2*kb].x);   p.us[1]=f2bf(a[2*kb].y);
    p.us[2]=f2bf(a[2*kb].z);   p.us[3]=f2bf(a[2*kb].w);
    p.us[4]=f2bf(a[2*kb+1].x); p.us[5]=f2bf(a[2*kb+1].y);
    p.us[6]=f2bf(a[2*kb+1].z); p.us[7]=f2bf(a[2*kb+1].w);
    *(uint4*)&As[kb][sW] = p.q;
  }
  __syncthreads();                      // covers As AND nbu

  f32x4_t acc[4][2];
  #pragma unroll
  for (int m = 0; m < 4; ++m)
    #pragma unroll
    for (int n = 0; n < 2; ++n)
      acc[m][n] = (f32x4_t){0.f, 0.f, 0.f, 0.f};

  #pragma unroll
  for (int kg = 0; kg < 8; ++kg) {
    int kb = kg >> 1, kc = kg & 1;
    bf16x8_t bn[2];
    #pragma unroll
    for (int n = 0; n < 2; ++n)
      bn[n] = *(const bf16x8_t*)(Wb2 + (size_t)(kg * 24 + wv * 2 + n) * 512 + lane * 8);
    #pragma unroll
    for (int m = 0; m < 4; ++m) {
      int row = m * 16 + (lane & 15);
      int seg = (kc * 4 + (lane >> 4)) ^ (row & 7);
      bf16x8_t af = *(const bf16x8_t*)&As[kb][row * 64 + seg * 8];
      #pragma unroll
      for (int n = 0; n < 2; ++n)
        acc[m][n] = __builtin_amdgcn_mfma_f32_16x16x32_bf16(af, bn[n], acc[m][n], 0, 0, 0);
    }
  }

  // Epilogue: out = acc + bias (+ nb for cols<128), single write
  const int l15 = lane & 15, lq = lane >> 4;
  const unsigned short* nb16 = (const unsigned short*)nbu;
  #pragma unroll
  for (int n = 0; n < 2; ++n) {
    int col = wv * 32 + n * 16 + l15;             // 0..255
    float bias = w0_b[col];
    #pragma unroll
    for (int m = 0; m < 4; ++m) {
      int rb = m * 16 + lq * 4;                   // local row
      #pragma unroll
      for (int r = 0; r < 4; ++r) {
        float v = acc[m][n][r] + bias;
        if (wv < 4) v += bf2f(nb16[(rb + r) * 130 + col]);   // wave-uniform branch
        out[(size_t)(mBase + rb + r) * 256 + col] = v;
      }
    }
  }
}

// ---------------------------------------------------------------------------
// CSR build
// ---------------------------------------------------------------------------
__global__ void count_deg(const int* __restrict__ edges, int* __restrict__ deg) {
  int i = blockIdx.x * blockDim.x + threadIdx.x;
  if (i >= 2 * E) return;
  int e = i >> 1, half = i & 1;
  atomicAdd(&deg[edges[2 * e + half]], 1);
}

__global__ void scan1(const int* __restrict__ deg, int* __restrict__ rowptr,
                      int* __restrict__ bsums) {
  __shared__ int sm[256];
  int i = blockIdx.x * 256 + threadIdx.x;
  int v = (i < V) ? deg[i] : 0;
  sm[threadIdx.x] = v;
  __syncthreads();
  for (int off = 1; off < 256; off <<= 1) {
    int t = (threadIdx.x >= off) ? sm[threadIdx.x - off] : 0;
    __syncthreads();
    sm[threadIdx.x] += t;
    __syncthreads();
  }
  if (i < V) rowptr[i] = sm[threadIdx.x] - v;
  if (threadIdx.x == 255) bsums[blockIdx.x] = sm[255];
}

__global__ void scan2(int* __restrict__ bsums) {
  __shared__ int sm[1024];
  int t = threadIdx.x;
  int v = (t < NB1) ? bsums[t] : 0;
  sm[t] = v;
  __syncthreads();
  for (int off = 1; off < 1024; off <<= 1) {
    int x = (t >= off) ? sm[t - off] : 0;
    __syncthreads();
    sm[t] += x;
    __syncthreads();
  }
  if (t < NB1) bsums[t] = sm[t] - v;
}

__global__ void scan3(int* __restrict__ rowptr, const int* __restrict__ bsums,
                      int* __restrict__ cursor) {
  int i = blockIdx.x * 256 + threadIdx.x;
  if (i < V) {
    int r = rowptr[i] + bsums[blockIdx.x];
    rowptr[i] = r;
    cursor[i] = r;
  }
  if (i == 0) rowptr[V] = 2 * E;
}

__global__ void fill_adj(const int* __restrict__ edges, int* __restrict__ cursor,
                         int* __restrict__ adj) {
  int i = blockIdx.x * blockDim.x + threadIdx.x;
  if (i >= 2 * E) return;
  int e = i >> 1, half = i & 1;
  int dst = edges[2 * e + half];
  int src = edges[2 * e + (half ^ 1)];
  adj[atomicAdd(&cursor[dst], 1)] = src;
}

// ---------------------------------------------------------------------------
extern "C" void kernel_launch(void* const* d_in, const int* in_sizes, int n_in,
                              void* d_out, int out_size, void* d_ws, size_t ws_size,
                              hipStream_t stream)
{
  const float* verts = (const float*)d_in[0];
  const int*   edges = (const int*)d_in[1];
  const float* w0_w  = (const float*)d_in[2];
  const float* w0_b  = (const float*)d_in[3];
  const float* w1_w  = (const float*)d_in[4];
  const float* w1_b  = (const float*)d_in[5];
  float* out = (float*)d_out;
  char*  ws  = (char*)d_ws;

  // workspace layout (bytes), total ~58.8 MB
  unsigned short* w1b = (unsigned short*)(ws);            // V*128*2 = 51,200,000
  int* rowptr = (int*)(ws + 51200000);                    // (V+1)*4
  int* cursor = (int*)(ws + 52000256);                    // V*4
  int* adj    = (int*)(ws + 52800256);                    // 2E*4 = 4,800,000
  int* deg    = (int*)(ws + 57600256);                    // V*4
  int* bsums  = (int*)(ws + 58400256);                    // 1024*4
  unsigned short* Wb2 = (unsigned short*)(ws + 58404352); // 98304*2*2 = 393,216

  hipMemsetAsync(deg, 0, V * sizeof(int), stream);
  prep_w2<<<384, 256, 0, stream>>>(w0_w, w1_w, Wb2);
  count_deg<<<(2 * E + 255) / 256, 256, 0, stream>>>(edges, deg);
  scan1<<<NB1, 256, 0, stream>>>(deg, rowptr, bsums);
  scan2<<<1, 1024, 0, stream>>>(bsums);
  scan3<<<NB1, 256, 0, stream>>>(rowptr, bsums, cursor);
  fill_adj<<<(2 * E + 255) / 256, 256, 0, stream>>>(edges, cursor, adj);

  gemm_w1<<<(V + 63) / 64, 512, 0, stream>>>(verts, Wb2, w1_b, w1b);

  gemm_w0_gather<<<(V + 63) / 64, 512, 0, stream>>>(
      verts, Wb2, w0_b, rowptr, adj, w1b, out);
}